// Round 11
// baseline (2139.636 us; speedup 1.0000x reference)
//
#include <hip/hip_runtime.h>

#define N_DIM 100000
#define M_DIM 200000
#define NNZ_A 2000000
#define NNZ_P 500000
#define NNZ_GN (NNZ_A + NNZ_P)
#define NMSUM 300000
#define NM1   300001
#define CG_ITERS 20
#define TPB 256
#define NSLOT 512
#define GOFF (20 * 5 * 64)            // gamma slots at red+GOFF, [21][64]
#define SETOFF (GOFF + 21 * 64)       // setup slots: xtpx,s1,s2,s3,s8,s9 each [64]
#define REDSZ (SETOFF + 6 * 64)
#define GN_BLKS ((N_DIM + TPB - 1) / TPB)   // 391
#define AR_BLKS ((M_DIM + TPB - 1) / TPB)   // 782

// sc[0]=xTPx, sc[16+it]=F_tau, sc[64+it]=gamma_it (published scalar)

__device__ __forceinline__ void blk_red_add(double v, double* dst) {
    __shared__ double sb[TPB];
    int tid = threadIdx.x;
    __syncthreads();
    sb[tid] = v;
    __syncthreads();
    for (int sh = TPB / 2; sh > 0; sh >>= 1) {
        if (tid < sh) sb[tid] += sb[tid + sh];
        __syncthreads();
    }
    if (tid == 0) atomicAdd(dst, sb[0]);
}

__device__ __forceinline__ void blk_red_add2(double v1, double v2, double* d1, double* d2) {
    __shared__ double sb1[TPB];
    __shared__ double sb2[TPB];
    int tid = threadIdx.x;
    __syncthreads();
    sb1[tid] = v1; sb2[tid] = v2;
    __syncthreads();
    for (int sh = TPB / 2; sh > 0; sh >>= 1) {
        if (tid < sh) { sb1[tid] += sb1[tid + sh]; sb2[tid] += sb2[tid + sh]; }
        __syncthreads();
    }
    if (tid == 0) { atomicAdd(d1, sb1[0]); atomicAdd(d2, sb2[0]); }
}

__device__ __forceinline__ double blk_sum64w(const double* src) {
    __shared__ double bsh;
    int t = threadIdx.x;
    if (t < 64) {
        double v = src[t];
        v += __shfl_xor(v, 32); v += __shfl_xor(v, 16); v += __shfl_xor(v, 8);
        v += __shfl_xor(v, 4);  v += __shfl_xor(v, 2);  v += __shfl_xor(v, 1);
        if (t == 0) bsh = v;
    }
    __syncthreads();
    double r = bsh;
    __syncthreads();
    return r;
}

// full-row 2-pair int4 dot (rows padded even; pad = {0,0.0f} -> +0.0)
__device__ __forceinline__ double row_dotx4(const int4* __restrict__ pp, int b2, int e2,
                                            const double* __restrict__ vin) {
    double s = 0.0;
    int k = b2;
    for (; k + 4 <= e2; k += 4) {
        int4 a = pp[k], b = pp[k + 1], c = pp[k + 2], d = pp[k + 3];
        double g0 = vin[a.x], g1 = vin[a.z], g2 = vin[b.x], g3 = vin[b.z];
        double g4 = vin[c.x], g5 = vin[c.z], g6 = vin[d.x], g7 = vin[d.z];
        s += (double)__int_as_float(a.y) * g0;
        s += (double)__int_as_float(a.w) * g1;
        s += (double)__int_as_float(b.y) * g2;
        s += (double)__int_as_float(b.w) * g3;
        s += (double)__int_as_float(c.y) * g4;
        s += (double)__int_as_float(c.w) * g5;
        s += (double)__int_as_float(d.y) * g6;
        s += (double)__int_as_float(d.w) * g7;
    }
    for (; k < e2; ++k) {
        int4 a = pp[k];
        s += (double)__int_as_float(a.y) * vin[a.x];
        s += (double)__int_as_float(a.w) * vin[a.z];
    }
    return s;
}

// generic contiguous chunk [kb,ke) of int4 slots
__device__ __forceinline__ double chunk_dot(const int4* __restrict__ pp, int kb, int ke,
                                            const double* __restrict__ vin) {
    double s = 0.0;
    int k = kb;
    for (; k + 4 <= ke; k += 4) {
        int4 a = pp[k], b = pp[k + 1], c = pp[k + 2], d = pp[k + 3];
        double g0 = vin[a.x], g1 = vin[a.z], g2 = vin[b.x], g3 = vin[b.z];
        double g4 = vin[c.x], g5 = vin[c.z], g6 = vin[d.x], g7 = vin[d.z];
        s += (double)__int_as_float(a.y) * g0;
        s += (double)__int_as_float(a.w) * g1;
        s += (double)__int_as_float(b.y) * g2;
        s += (double)__int_as_float(b.w) * g3;
        s += (double)__int_as_float(c.y) * g4;
        s += (double)__int_as_float(c.w) * g5;
        s += (double)__int_as_float(d.y) * g6;
        s += (double)__int_as_float(d.w) * g7;
    }
    for (; k + 2 <= ke; k += 2) {
        int4 a = pp[k], b = pp[k + 1];
        double g0 = vin[a.x], g1 = vin[a.z], g2 = vin[b.x], g3 = vin[b.z];
        s += (double)__int_as_float(a.y) * g0;
        s += (double)__int_as_float(a.w) * g1;
        s += (double)__int_as_float(b.y) * g2;
        s += (double)__int_as_float(b.w) * g3;
    }
    if (k < ke) {
        int4 a = pp[k];
        s += (double)__int_as_float(a.y) * vin[a.x];
        s += (double)__int_as_float(a.w) * vin[a.z];
    }
    return s;
}

// 2-thread-per-row halves + 1 shfl
__device__ __forceinline__ double row_dotx4_half(const int4* __restrict__ pp, int b2, int e2,
                                                 const double* __restrict__ vin, int half) {
    int len = e2 - b2;
    int h1 = (len + 1) >> 1;
    int kb = b2 + (half ? h1 : 0);
    int ke = half ? e2 : (b2 + h1);
    double s = chunk_dot(pp, kb, ke, vin);
    s += __shfl_xor(s, 1);
    return s;
}

// 4-thread-per-row quarters + 2 shfls (contiguous chunks)
__device__ __forceinline__ double row_dotx4_quarter(const int4* __restrict__ pp, int b2, int e2,
                                                    const double* __restrict__ vin, int qd) {
    int len = e2 - b2;
    int h = (len + 3) >> 2;
    int kb = b2 + qd * h;
    int ke = kb + h;
    if (kb > e2) kb = e2;
    if (ke > e2) ke = e2;
    double s = chunk_dot(pp, kb, ke, vin);
    s += __shfl_xor(s, 1);
    s += __shfl_xor(s, 2);
    return s;
}

__device__ __forceinline__ double row_dot_d(const int2* __restrict__ pair,
                                            const float* __restrict__ dval, int beg, int end,
                                            const double* __restrict__ vin) {
    double s = 0.0;
    int k = beg;
    for (; k + 4 <= end; k += 4) {
        int c0 = pair[k].x, c1 = pair[k + 1].x, c2 = pair[k + 2].x, c3v = pair[k + 3].x;
        float d0 = dval[k], d1 = dval[k + 1], d2 = dval[k + 2], d3 = dval[k + 3];
        double g0 = vin[c0], g1 = vin[c1], g2 = vin[c2], g3 = vin[c3v];
        s += (double)d0 * g0;
        s += (double)d1 * g1;
        s += (double)d2 * g2;
        s += (double)d3 * g3;
    }
    for (; k < end; ++k)
        s += (double)dval[k] * vin[pair[k].x];
    return s;
}

// ---------------- setup ----------------
__global__ __launch_bounds__(TPB) void k_init(double* sc, const float* y, const float* s,
                                              const float* x, double* mask_d, double* xpim,
                                              double* xcg, double* red,
                                              int* nP, int* cntGn, int* cntAr) {
    long i = (long)blockIdx.x * TPB + threadIdx.x;
    if (i < NSLOT) sc[i] = 0.0;
    if (i < REDSZ) red[i] = 0.0;
    if (i < M_DIM) {
        double v = (double)y[i] - (double)s[i];
        mask_d[i] = v > 0.0 ? 1.0 : 0.0;
        xpim[N_DIM + i] = v > 0.0 ? v : 0.0;   // pi_m
        cntAr[i] = 0;
    }
    if (i < N_DIM) {
        xpim[i] = (double)x[i];
        nP[i] = 0; cntGn[i] = 0;
    }
    if (i < NM1) xcg[i] = 0.0;
}

// histogram; atomic returns = within-row sequence numbers (NT-stored, reused by fills)
__global__ __launch_bounds__(TPB) void k_hist(const int* Ar, const int* Ac, const int* Pr,
                                              int* nP, int* cntGn, int* cntAr,
                                              int* seqP, int* seqGn, int* seqAr) {
    long k = (long)blockIdx.x * TPB + threadIdx.x;
    if (k < NNZ_A) {
        int sg = atomicAdd(&cntGn[Ac[k]], 1);
        int sa = atomicAdd(&cntAr[Ar[k]], 1);
        __builtin_nontemporal_store(sg, &seqGn[k]);
        __builtin_nontemporal_store(sa, &seqAr[k]);
    }
    if (k < NNZ_P) {
        int sp = atomicAdd(&nP[Pr[k]], 1);
        __builtin_nontemporal_store(sp, &seqP[k]);
    }
}

// merged both-matrix scan, pass 1: per-block inclusive scan of even-padded lengths.
// Gn blocks also fold nP into cntGn (raw combined length stored back).
__global__ __launch_bounds__(TPB) void k_scan1b(const int* nP, int* cntGn, const int* cntAr,
                                                int* rptrGn, int* rptrAr, int* blksum) {
    __shared__ int sb[TPB];
    int bid = blockIdx.x;
    int t = threadIdx.x;
    int c = 0;
    int i;
    bool isGn = bid < GN_BLKS;
    if (isGn) {
        i = bid * TPB + t;
        if (i < N_DIM) { c = cntGn[i] + nP[i]; cntGn[i] = c; }
    } else {
        i = (bid - GN_BLKS) * TPB + t;
        if (i < M_DIM) c = cntAr[i];
    }
    int v = c + (c & 1);
    sb[t] = v;
    __syncthreads();
    for (int sh = 1; sh < TPB; sh <<= 1) {
        int u = (t >= sh) ? sb[t - sh] : 0;
        __syncthreads();
        sb[t] += u;
        __syncthreads();
    }
    if (isGn) { if (i < N_DIM) rptrGn[i] = sb[t] - v; }
    else      { if (i < M_DIM) rptrAr[i] = sb[t] - v; }
    if (t == TPB - 1) blksum[bid] = sb[TPB - 1];
}

// pass 2: two blocks scan the two blksum segments, write totals
__global__ __launch_bounds__(1024) void k_scan2b(int* blksum, int* rptrGn, int* rptrAr) {
    __shared__ int sb[1024];
    int t = threadIdx.x;
    int base = (blockIdx.x == 0) ? 0 : GN_BLKS;
    int nb = (blockIdx.x == 0) ? GN_BLKS : AR_BLKS;
    int v = (t < nb) ? blksum[base + t] : 0;
    sb[t] = v;
    __syncthreads();
    for (int sh = 1; sh < 1024; sh <<= 1) {
        int x = (t >= sh) ? sb[t - sh] : 0;
        __syncthreads();
        sb[t] += x;
        __syncthreads();
    }
    if (t < nb) blksum[base + t] = sb[t] - v;
    if (t == nb - 1) {
        if (blockIdx.x == 0) rptrGn[N_DIM] = sb[t];
        else                 rptrAr[M_DIM] = sb[t];
    }
}

// pass 3: add block offsets
__global__ __launch_bounds__(TPB) void k_scan3b(int* rptrGn, int* rptrAr, const int* blksum) {
    int bid = blockIdx.x;
    int t = threadIdx.x;
    if (bid < GN_BLKS) {
        int i = bid * TPB + t;
        if (i < N_DIM) rptrGn[i] += blksum[bid];
    } else {
        int i = (bid - GN_BLKS) * TPB + t;
        if (i < M_DIM) rptrAr[i] += blksum[bid];
    }
}

// atomic-FREE fill of G_n (P part + A^T part)
__global__ __launch_bounds__(TPB) void k_fillGn(const int* Pr, const int* Pc, const float* Pv,
                                                const float* dPv,
                                                const int* Ar, const int* Ac, const float* Av,
                                                const float* dAv,
                                                const int* rptrGn, const int* nP,
                                                const int* seqP, const int* seqGn,
                                                int2* pGn, float* dvalGn) {
    long k = (long)blockIdx.x * TPB + threadIdx.x;
    if (k < NNZ_P) {
        int r0 = Pr[k];
        int pos = rptrGn[r0] + seqP[k];
        pGn[pos] = make_int2(Pc[k], __float_as_int(Pv[k]));
        dvalGn[pos] = dPv[k];
    }
    if (k < NNZ_A) {
        int c0 = Ac[k];
        int pos = rptrGn[c0] + nP[c0] + seqGn[k];
        pGn[pos] = make_int2(N_DIM + Ar[k], __float_as_int(Av[k]));
        dvalGn[pos] = dAv[k];
    }
}

// atomic-FREE fill of A-by-row + pad slots for BOTH matrices
__global__ __launch_bounds__(TPB) void k_fillArPad(const int* Ar, const int* Ac, const float* Av,
                                                   const float* dAv, const int* rptrAr,
                                                   const int* seqAr, int2* pAr, float* dvalAr,
                                                   const int* cntGn, const int* rptrGn,
                                                   int2* pGn, float* dvalGn, const int* cntAr) {
    long k = (long)blockIdx.x * TPB + threadIdx.x;
    if (k < NNZ_A) {
        int pos = rptrAr[Ar[k]] + seqAr[k];
        pAr[pos] = make_int2(Ac[k], __float_as_int(Av[k]));
        dvalAr[pos] = dAv[k];
    }
    if (k < N_DIM) {
        int c = cntGn[k];
        if (c & 1) { int pos = rptrGn[k] + c; pGn[pos] = make_int2(0, 0); dvalGn[pos] = 0.0f; }
    }
    if (k < M_DIM) {
        int c = cntAr[k];
        if (c & 1) { int pos = rptrAr[k] + c; pAr[pos] = make_int2(0, 0); dvalAr[pos] = 0.0f; }
    }
}

// merged setup: n-part {c3, dd_n, dots xtpx,dq.x,x.dpx} + m-part {dd_m, dot db.pim}
__global__ __launch_bounds__(TPB) void k_setup(const int* __restrict__ rptrGn,
                                               const int2* __restrict__ pGn,
                                               const float* __restrict__ dvalGn,
                                               const int* __restrict__ nP,
                                               const int* __restrict__ rptrAr,
                                               const int2* __restrict__ pAr,
                                               const float* __restrict__ dvalAr,
                                               const double* __restrict__ xpim,
                                               const float* __restrict__ q,
                                               const float* __restrict__ dq,
                                               const float* __restrict__ db,
                                               double* c3, double* dd, double* red) {
    int i = blockIdx.x * TPB + threadIdx.x;
    int slot = blockIdx.x & 63;
    double* S = red + SETOFF;
    double lx = 0.0, l1 = 0.0, l2 = 0.0, l3 = 0.0;
    if (i < N_DIM) {
        int beg = rptrGn[i], end = rptrGn[i + 1];
        int np = nP[i];
        double px = 0.0, dpxv = 0.0, sa = 0.0;
        for (int k = beg; k < end; ++k) {
            int2 e = pGn[k];
            float dv = dvalGn[k];
            double g = xpim[e.x];
            if (k - beg < np) {
                px += (double)__int_as_float(e.y) * g;
                dpxv += (double)dv * g;
            } else {
                sa += (double)dv * g;
            }
        }
        c3[i] = (double)q[i] + 2.0 * px;
        dd[i] = dpxv + sa + (double)dq[i];
        double xi = xpim[i];
        lx = xi * px;
        l1 = (double)dq[i] * xi;
        l3 = xi * dpxv;
    }
    if (i < M_DIM) {
        double s = row_dot_d(pAr, dvalAr, rptrAr[i], rptrAr[i + 1], xpim);
        dd[N_DIM + i] = -s + (double)db[i];
        l2 = (double)db[i] * xpim[N_DIM + i];
    }
    blk_red_add2(lx, l1, S + 0 * 64 + slot, S + 1 * 64 + slot);   // xTPx, dq.x
    blk_red_add2(l3, l2, S + 3 * 64 + slot, S + 2 * 64 + slot);   // x.dpx, db.pim
}

// dd = -dd ; WC = [W_n ; -W_m]; tau thread: dd[NMSUM] & sc[0]; slot-dots {q.W_n, b.W_m}
__global__ __launch_bounds__(TPB) void k_negWC(double* dd, double* WC,
                                               const float* q, const float* b,
                                               double* red, double* sc) {
    long i = (long)blockIdx.x * TPB + threadIdx.x;
    int slot = blockIdx.x & 63;
    double* S = red + SETOFF;
    double l8 = 0.0, l9 = 0.0;
    if (i == NMSUM) {
        double xt = 0.0, s1 = 0.0, s2 = 0.0, s3 = 0.0;
        for (int k = 0; k < 64; ++k) {
            xt += S[k]; s1 += S[64 + k]; s2 += S[128 + k]; s3 += S[192 + k];
        }
        sc[0] = xt;
        dd[NMSUM] = s1 + s2 + s3;
    } else if (i < NM1) {
        double nv = -dd[i];
        dd[i] = nv;
        if (i < N_DIM) {
            WC[i] = nv;
            l8 = (double)q[i] * nv;
        } else {
            WC[i] = -nv;
            l9 = (double)b[i - N_DIM] * nv;
        }
    }
    blk_red_add2(l8, l9, S + 4 * 64 + slot, S + 5 * 64 + slot);
}

// merged r_n, r_m, r_tau + cginit (p=r, gamma0 slots)
__global__ __launch_bounds__(TPB) void k_r(const int* __restrict__ rptrGn, const int2* __restrict__ pGn,
                                           const int* __restrict__ rptrAr, const int2* __restrict__ pAr,
                                           const double* __restrict__ WC, const double* __restrict__ c3,
                                           const double* __restrict__ mask_d, const float* __restrict__ b,
                                           const double* __restrict__ dd, double* r, double* p,
                                           double* red, const double* sc) {
    const int4* pGn4 = (const int4*)pGn;
    const int4* pAr4 = (const int4*)pAr;
    long i = (long)blockIdx.x * TPB + threadIdx.x;
    int slot = blockIdx.x & 63;
    double* S = red + SETOFF;
    double* gslot = red + GOFF;
    double rv = 0.0;
    bool wr = false;
    if (i < N_DIM) {
        double s = row_dotx4(pGn4, rptrGn[i] >> 1, rptrGn[i + 1] >> 1, WC);
        rv = s - c3[i] * dd[NMSUM];
        wr = true;
    } else if (i < NMSUM) {
        int j = (int)(i - N_DIM);
        double s = row_dotx4(pAr4, rptrAr[j] >> 1, rptrAr[j + 1] >> 1, WC);
        double wt = dd[NMSUM];
        double tmv = s - (double)b[j] * wt;
        double wm = dd[i];
        rv = mask_d[j] * (tmv - wm) + wm;
        wr = true;
    } else if (i == NMSUM) {
        double e1 = 0.0, e2 = 0.0;
        for (int k = 0; k < 64; ++k) { e1 += S[4 * 64 + k]; e2 += S[5 * 64 + k]; }
        rv = e1 + e2 + sc[0] * dd[NMSUM];
        wr = true;
    }
    double l = 0.0;
    if (wr) { r[i] = rv; p[i] = rv; l = rv * rv; }
    blk_red_add(l, gslot + slot);
}

// ---------------- per-iteration kernels (4 launches/iter) ----------------
// K1: p-update + pum + d1,d2; gamma published by block 0 to sc[64+it]
__global__ __launch_bounds__(TPB) void k_iterA(const double* r, double* p,
                                               const double* mask_d, const double* c3,
                                               const float* b, double* pum,
                                               double* red, double* sc, int it) {
    double* ds = red + (long)it * 5 * 64;
    double* gslot = red + GOFF;
    double gn = blk_sum64w(gslot + (long)it * 64);
    if (blockIdx.x == 0 && threadIdx.x == 0) sc[64 + it] = gn;
    double beta = 0.0;
    if (it > 0) beta = gn / sc[64 + it - 1];
    long i = (long)blockIdx.x * TPB + threadIdx.x;
    int slot = blockIdx.x & 63;
    double l1 = 0.0, l2 = 0.0;
    if (i < NM1) {
        double pn;
        if (it > 0) {
            pn = r[i] + beta * p[i];
            p[i] = pn;
        } else {
            pn = p[i];
        }
        if (i < N_DIM) {
            l1 = c3[i] * pn;
            pum[i] = pn;
        } else if (i < NMSUM) {
            int j = (int)(i - N_DIM);
            double u = mask_d[j] * pn;
            pum[i] = u;
            l2 = (double)b[j] * u;
        }
    }
    blk_red_add2(l1, l2, ds + 0 * 64 + slot, ds + 1 * 64 + slot);
}

// K2: Fmv — n-side 4-thread/row quarters, m-side 2-thread/row halves; idle last block: F_tau
__global__ __launch_bounds__(TPB) void k_fmv(const int* __restrict__ rptrGn, const int2* __restrict__ pGn,
                                             const int* __restrict__ rptrAr, const int2* __restrict__ pAr,
                                             const float* __restrict__ q, const float* __restrict__ b,
                                             const double* __restrict__ p, const double* __restrict__ pum,
                                             double* __restrict__ Fpc, double* sc, double* red, int it) {
    const int4* pGn4 = (const int4*)pGn;
    const int4* pAr4 = (const int4*)pAr;
    double* ds = red + (long)it * 5 * 64;
    long t = (long)blockIdx.x * TPB + threadIdx.x;
    int slot = blockIdx.x & 63;
    double ut = p[NMSUM];
    double l1 = 0.0, l2 = 0.0;
    if (t < 4L * N_DIM) {
        int i = (int)(t >> 2);
        int qd = (int)(t & 3);
        double s = row_dotx4_quarter(pGn4, rptrGn[i] >> 1, rptrGn[i + 1] >> 1, pum, qd);
        if (qd == 0) {
            double r1 = s + (double)q[i] * ut;
            double v = (r1 - p[i]) + p[i];
            Fpc[i] = v;
            l1 = (double)q[i] * v;
        }
    } else if (t < 4L * N_DIM + 2L * M_DIM) {
        long u = t - 4L * N_DIM;
        int j = (int)(u >> 1);
        int half = (int)(u & 1);
        int gj = N_DIM + j;
        double s = row_dotx4_half(pAr4, rptrAr[j] >> 1, rptrAr[j + 1] >> 1, pum, half);
        if (half == 0) {
            double r2 = -s + (double)b[j] * ut;
            double v = (r2 - pum[gj]) + p[gj];
            Fpc[gj] = -v;
            l2 = (double)b[j] * v;
        }
    }
    blk_red_add2(l1, l2, ds + 2 * 64 + slot, ds + 3 * 64 + slot);
    if (blockIdx.x == gridDim.x - 1) {
        double d1 = blk_sum64w(ds + 0 * 64);
        double d2 = blk_sum64w(ds + 1 * 64);
        if (threadIdx.x == 0) {
            double r3 = -d1 - d2 + sc[0] * ut;
            sc[16 + it] = (r3 - ut) + ut;   // F_tau
        }
    }
}

// K3: FTmv — same decomposition over Fpc; Ap + pq; idle last block: tau row
__global__ __launch_bounds__(TPB) void k_ftmv(const int* __restrict__ rptrGn, const int2* __restrict__ pGn,
                                              const int* __restrict__ rptrAr, const int2* __restrict__ pAr,
                                              const float* __restrict__ b, const double* __restrict__ mask_d,
                                              const double* __restrict__ c3,
                                              const double* __restrict__ Fpc, const double* __restrict__ p,
                                              double* __restrict__ Ap, double* sc, double* red, int it) {
    const int4* pGn4 = (const int4*)pGn;
    const int4* pAr4 = (const int4*)pAr;
    double* ds = red + (long)it * 5 * 64;
    long t = (long)blockIdx.x * TPB + threadIdx.x;
    int slot = blockIdx.x & 63;
    double wt = sc[16 + it];
    double l = 0.0;
    if (t < 4L * N_DIM) {
        int i = (int)(t >> 2);
        int qd = (int)(t & 3);
        double s = row_dotx4_quarter(pGn4, rptrGn[i] >> 1, rptrGn[i + 1] >> 1, Fpc, qd);
        if (qd == 0) {
            double v = s - c3[i] * wt;
            Ap[i] = v;
            l = p[i] * v;
        }
    } else if (t < 4L * N_DIM + 2L * M_DIM) {
        long u = t - 4L * N_DIM;
        int j = (int)(u >> 1);
        int half = (int)(u & 1);
        int gj = N_DIM + j;
        double s = row_dotx4_half(pAr4, rptrAr[j] >> 1, rptrAr[j + 1] >> 1, Fpc, half);
        if (half == 0) {
            double tmv = s - (double)b[j] * wt;
            double wm = -Fpc[gj];
            double v = mask_d[j] * (tmv - wm) + wm;
            Ap[gj] = v;
            l = p[gj] * v;
        }
    }
    blk_red_add(l, ds + 4 * 64 + slot);
    if (blockIdx.x == gridDim.x - 1) {
        double e1 = blk_sum64w(ds + 2 * 64);
        double e2 = blk_sum64w(ds + 3 * 64);
        if (threadIdx.x == 0) {
            double tt = e1 + e2 + sc[0] * wt;
            Ap[NMSUM] = tt;
            atomicAdd(ds + 4 * 64 + slot, p[NMSUM] * tt);
        }
    }
}

// K4: alpha, x/r update + gam[it+1] slots
__global__ __launch_bounds__(TPB) void k_upd(const double* p, const double* Ap,
                                             double* xcg, double* r, double* red,
                                             const double* sc, int it) {
    double* ds = red + (long)it * 5 * 64;
    double* gslot = red + GOFF;
    double gcur = sc[64 + it];
    double pq = blk_sum64w(ds + 4 * 64);
    double alpha = gcur / pq;
    long i = (long)blockIdx.x * TPB + threadIdx.x;
    int slot = blockIdx.x & 63;
    double l = 0.0;
    if (i < NM1) {
        xcg[i] += alpha * p[i];
        double rn = r[i] - alpha * Ap[i];
        r[i] = rn;
        l = rn * rn;
    }
    blk_red_add(l, gslot + (long)(it + 1) * 64 + slot);
}

__global__ __launch_bounds__(TPB) void k_final(const double* xcg, const double* mask_d,
                                               const float* x, const float* y, const float* s,
                                               float* out) {
    int i = blockIdx.x * TPB + threadIdx.x;
    double dzt = xcg[NMSUM];
    if (i < N_DIM) {
        out[i] = (float)(xcg[i] - (double)x[i] * dzt);
    } else if (i < NMSUM) {
        int j = i - N_DIM;
        double dzm = xcg[N_DIM + j];
        double t = mask_d[j] * dzm;
        out[N_DIM + j] = (float)(t - (double)y[j] * dzt);
        out[N_DIM + M_DIM + j] = (float)(t - dzm - (double)s[j] * dzt);
    }
}

extern "C" void kernel_launch(void* const* d_in, const int* in_sizes, int n_in,
                              void* d_out, int out_size, void* d_ws, size_t ws_size,
                              hipStream_t stream) {
    const int*   Pr  = (const int*)d_in[0];
    const int*   Pc  = (const int*)d_in[1];
    const float* Pv  = (const float*)d_in[2];
    const int*   Ar  = (const int*)d_in[3];
    const int*   Ac  = (const int*)d_in[4];
    const float* Av  = (const float*)d_in[5];
    const float* q   = (const float*)d_in[6];
    const float* b   = (const float*)d_in[7];
    const float* x   = (const float*)d_in[8];
    const float* yv  = (const float*)d_in[9];
    const float* sv  = (const float*)d_in[10];
    const float* dPv = (const float*)d_in[11];
    const float* dAv = (const float*)d_in[12];
    const float* dq  = (const float*)d_in[13];
    const float* db  = (const float*)d_in[14];
    float* out = (float*)d_out;

    char* wp = (char*)d_ws;
    auto alloc = [&](size_t bytes) { char* r0 = wp; wp += (bytes + 255) & ~255ull; return r0; };

    double* sc     = (double*)alloc(NSLOT * 8);
    double* red    = (double*)alloc((size_t)REDSZ * 8);
    double* mask_d = (double*)alloc((size_t)M_DIM * 8);
    double* xpim   = (double*)alloc((size_t)NMSUM * 8);   // [x ; pi_m]
    double* c3     = (double*)alloc((size_t)N_DIM * 8);
    double* dd     = (double*)alloc((size_t)NM1 * 8);
    double* r      = (double*)alloc((size_t)NM1 * 8);
    double* p      = (double*)alloc((size_t)NM1 * 8);
    double* xcg    = (double*)alloc((size_t)NM1 * 8);
    double* Ap     = (double*)alloc((size_t)NM1 * 8);
    double* pum    = (double*)alloc((size_t)NMSUM * 8);   // [p_n ; um]
    double* Fpc    = (double*)alloc((size_t)NMSUM * 8);   // [Fp_n ; -Fp_m]
    double* WC     = (double*)alloc((size_t)NMSUM * 8);   // [W_n ; -W_m]
    int2*  pGn    = (int2*)alloc(((size_t)NNZ_GN + N_DIM) * 8);
    int2*  pAr    = (int2*)alloc(((size_t)NNZ_A + M_DIM) * 8);
    float* dvalGn = (float*)alloc(((size_t)NNZ_GN + N_DIM) * 4);
    float* dvalAr = (float*)alloc(((size_t)NNZ_A + M_DIM) * 4);
    int*   rptrGn = (int*)alloc((size_t)(N_DIM + 1) * 4);
    int*   rptrAr = (int*)alloc((size_t)(M_DIM + 1) * 4);
    int*   nP     = (int*)alloc((size_t)N_DIM * 4);
    int*   cntGn  = (int*)alloc((size_t)N_DIM * 4);
    int*   cntAr  = (int*)alloc((size_t)M_DIM * 4);
    int*   seqP   = (int*)alloc((size_t)NNZ_P * 4);
    int*   seqGn  = (int*)alloc((size_t)NNZ_A * 4);
    int*   seqAr  = (int*)alloc((size_t)NNZ_A * 4);
    int*   blks   = (int*)alloc(2048 * 4);

    auto g = [](long n) { return dim3((unsigned)((n + TPB - 1) / TPB)); };
    dim3 gs((unsigned)((4L * N_DIM + 2L * M_DIM) / TPB + 1));   // 3125 work blocks + 1 idle
    dim3 gscan((unsigned)(GN_BLKS + AR_BLKS));

    // ---- CSR build ----
    hipLaunchKernelGGL(k_init, g(NM1), dim3(TPB), 0, stream, sc, yv, sv, x, mask_d, xpim, xcg, red,
                       nP, cntGn, cntAr);
    hipLaunchKernelGGL(k_hist, g(NNZ_A), dim3(TPB), 0, stream, Ar, Ac, Pr, nP, cntGn, cntAr,
                       seqP, seqGn, seqAr);
    hipLaunchKernelGGL(k_scan1b, gscan, dim3(TPB), 0, stream, nP, cntGn, cntAr, rptrGn, rptrAr, blks);
    hipLaunchKernelGGL(k_scan2b, dim3(2), dim3(1024), 0, stream, blks, rptrGn, rptrAr);
    hipLaunchKernelGGL(k_scan3b, gscan, dim3(TPB), 0, stream, rptrGn, rptrAr, blks);

    hipLaunchKernelGGL(k_fillGn, g(NNZ_A), dim3(TPB), 0, stream, Pr, Pc, Pv, dPv,
                       Ar, Ac, Av, dAv, rptrGn, nP, seqP, seqGn, pGn, dvalGn);
    hipLaunchKernelGGL(k_fillArPad, g(NNZ_A), dim3(TPB), 0, stream, Ar, Ac, Av, dAv,
                       rptrAr, seqAr, pAr, dvalAr, cntGn, rptrGn, pGn, dvalGn, cntAr);

    // ---- setup math (fused) ----
    hipLaunchKernelGGL(k_setup, g(M_DIM), dim3(TPB), 0, stream, rptrGn, pGn, dvalGn, nP,
                       rptrAr, pAr, dvalAr, xpim, q, dq, db, c3, dd, red);
    hipLaunchKernelGGL(k_negWC, g(NM1), dim3(TPB), 0, stream, dd, WC, q, b, red, sc);
    hipLaunchKernelGGL(k_r, g(NM1), dim3(TPB), 0, stream, rptrGn, pGn, rptrAr, pAr,
                       WC, c3, mask_d, b, dd, r, p, red, sc);

    // ---- 20 CG iterations, 4 launches each ----
    for (int it = 0; it < CG_ITERS; ++it) {
        hipLaunchKernelGGL(k_iterA, g(NM1), dim3(TPB), 0, stream, r, p, mask_d, c3, b, pum, red, sc, it);
        hipLaunchKernelGGL(k_fmv,   gs, dim3(TPB), 0, stream, rptrGn, pGn, rptrAr, pAr,
                           q, b, p, pum, Fpc, sc, red, it);
        hipLaunchKernelGGL(k_ftmv,  gs, dim3(TPB), 0, stream, rptrGn, pGn, rptrAr, pAr,
                           b, mask_d, c3, Fpc, p, Ap, sc, red, it);
        hipLaunchKernelGGL(k_upd,   g(NM1), dim3(TPB), 0, stream, p, Ap, xcg, r, red, sc, it);
    }

    hipLaunchKernelGGL(k_final, g(NMSUM), dim3(TPB), 0, stream, xcg, mask_d, x, yv, sv, out);
}